// Round 1
// 201.536 us; speedup vs baseline: 1.6307x; 1.6307x over previous
//
#include <hip/hip_runtime.h>
#include <hip/hip_bf16.h>
#include <stdint.h>

#define NF 51
#define NF2 (51*51)
#define WIN 100
#define EMB 12
#define FIN 112
#define HID 60
#define NPRUNE 1561
#define SORTN 4096

// ws byte offsets (total 96064 B) — contiguous; forward stages with ONE linear copy
#define WS_ADJ   0          // f16 [64][72]   adj[m][k] (m,k<51 else 0)
#define WS_WX    9216       // f16 [112][136] Wx[n][k]  (n<100,k<100 else 0)
#define WS_W1    39680      // f16 [64][136]  w1[n][k]  (n<60,k<100 else 0)
#define WS_W2    57088      // f16 [112][72]  w2[n][k]  (n<100,k<60 else 0)
#define WS_D     73216      // f32 [51][112]  D = norm_adj@C_emb + gcn_b (col<100 else 0)
#define WS_TOTAL 96064

// forward LDS layout (bytes)
#define LDS_R1   96064      // f16 [120][136]  sX (x rows) / h2, alternating
#define LDS_R2   128704     // f16 yT [2][112][72]  /  h3 [120][72], alternating
#define LDS_TOTAL 160960

typedef _Float16 f16;
typedef _Float16 f16x8 __attribute__((ext_vector_type(8)));
typedef _Float16 f16x4 __attribute__((ext_vector_type(4)));
typedef float f32x4 __attribute__((ext_vector_type(4)));

__device__ __forceinline__ float fast_tanh(float x) {
  float xa = fminf(fmaxf(x, -15.f), 15.f);
  float e = __expf(2.f * xa);
  return (e - 1.f) * __builtin_amdgcn_rcpf(e + 1.f);
}

// ---------------- Kernel 1: graph construction + greedy prune + prep ----------------
__global__ __launch_bounds__(512) void prune_kernel(const float* __restrict__ embed,
                                                    const float* __restrict__ gcn_w,
                                                    const float* __restrict__ gcn_b,
                                                    const float* __restrict__ w1,
                                                    const float* __restrict__ w2,
                                                    void* __restrict__ ws) {
  __shared__ float sA[NF * 52];
  __shared__ unsigned long long sKey[SORTN];
  __shared__ float sNrm[NF];
  __shared__ float sDinv[NF];
  __shared__ float sRow[NF];
  __shared__ float sCol[NF];
  __shared__ float sEmb[NF * EMB];
  __shared__ float sE2[NF * EMB];
  __shared__ int sCnt[17];
  const int t = threadIdx.x;

  for (int u = t; u < NF * EMB; u += 512) sEmb[u] = embed[u];
  __syncthreads();
  if (t < NF) {
    float s = 0.f;
    for (int e = 0; e < EMB; e++) { float w = sEmb[t*EMB + e]; s += w * w; }
    sNrm[t] = sqrtf(s);
  }
  __syncthreads();
  for (int u = t; u < NF2; u += 512) {
    int r = u / NF, c = u % NF;
    float d = 0.f;
    for (int e = 0; e < EMB; e++) d += sEmb[r*EMB + e] * sEmb[c*EMB + e];
    sA[r*52 + c] = d / (sNrm[r] * sNrm[c]);
  }
  __syncthreads();

  // ---- negatives-only compaction: phase-1 walk never consumes non-negative
  // values (first non-negative blocking entry => toP2, and phase 2 scans sA
  // directly), so only negatives need sorting. ~1275 of 2601 are negative =>
  // sort 2048 instead of 4096; fallback to 4096 keeps it correct regardless.
  int myCnt = 0;
  for (int u = t; u < NF2; u += 512)
    myCnt += (sA[(u / NF)*52 + (u % NF)] < 0.f) ? 1 : 0;
  int incl = myCnt;
  for (int o = 1; o < 64; o <<= 1) {
    int nb = __shfl_up(incl, o, 64);
    if ((t & 63) >= o) incl += nb;
  }
  if ((t & 63) == 63) sCnt[t >> 6] = incl;
  __syncthreads();
  if (t == 0) {
    int run = 0;
    for (int j = 0; j < 8; j++) { int v = sCnt[j]; sCnt[8 + j] = run; run += v; }
    sCnt[16] = run;
  }
  __syncthreads();
  const int total = sCnt[16];
  const int n = (total <= 2048) ? 2048 : SORTN;
  {
    int cpos = sCnt[8 + (t >> 6)] + (incl - myCnt);
    for (int u = t; u < NF2; u += 512) {
      float v = sA[(u / NF)*52 + (u % NF)];
      if (v < 0.f) {
        unsigned int b = __float_as_uint(v);   // negative => sign bit set => monotone map ~b
        sKey[cpos++] = ((unsigned long long)(~b) << 32) | (unsigned int)u;
      }
    }
    for (int u = total + t; u < n; u += 512) sKey[u] = ~0ull;
  }
  __syncthreads();
  // bitonic sort ascending over n (2048 typical)
  for (int kk = 2; kk <= n; kk <<= 1) {
    for (int jj = kk >> 1; jj > 0; jj >>= 1) {
      for (int u = t; u < n; u += 512) {
        int l = u ^ jj;
        if (l > u) {
          unsigned long long a = sKey[u], b = sKey[l];
          bool up = ((u & kk) == 0);
          if ((a > b) == up) { sKey[u] = b; sKey[l] = a; }
        }
      }
      __syncthreads();
    }
  }

  // row/col sums in LDS
  if (t < NF) {
    float rs = 0.f, cs = 0.f;
    for (int j = 0; j < NF; j++) { rs += sA[t*52 + j]; cs += sA[j*52 + t]; }
    sRow[t] = rs; sCol[t] = cs;
  }
  __syncthreads();

  // ---- greedy walk, wave 0: ballot-batched over sorted order ----
  // Soundness: during the negative phase every update (accept: -=v with v<0;
  // reject: += mx-v > 0) INCREASES sums, and ok = (sum - v > 0) is monotone in
  // sum. So ok evaluated with stale (round-start) sums is a lower bound:
  // the leading all-ok prefix of a chunk is exactly what the serial walk accepts.
  if (t < 64) {
    const int lane = t;
    float mx = -3.0e38f;
    for (int u = lane; u < NF2; u += 64) mx = fmaxf(mx, sA[(u / NF)*52 + (u % NF)]);
    for (int o = 32; o > 0; o >>= 1) mx = fmaxf(mx, __shfl_xor(mx, o, 64));

    int pruned = 0, pos = 0;
    bool toP2 = false;
    while (pruned < NPRUNE && !toP2) {
      int myi = pos + lane;
      unsigned long long kv = (myi < n) ? sKey[myi] : ~0ull;
      unsigned int mb  = (unsigned int)(kv >> 32);
      unsigned int idx = (unsigned int)kv;
      unsigned int vb  = (mb & 0x80000000u) ? (mb & 0x7FFFFFFFu) : ~mb;
      float v = __uint_as_float(vb);
      bool elig = (v < 0.f) && (idx < (unsigned)NF2);
      int r = 0, c2 = 0; bool okl = false;
      if (elig) {
        r = (int)(idx / NF); c2 = (int)(idx % NF);
        float sr = sRow[r], sc = sCol[c2];
        okl = ((sr - v) > 0.f) || ((sc - v) > 0.f);
      }
      unsigned long long bal = __ballot(okl);
      unsigned long long nb = ~bal;
      int nok = (nb == 0ull) ? 64 : (int)__builtin_ctzll(nb);
      int rem = NPRUNE - pruned;
      int take = nok < rem ? nok : rem;
      if (lane < take) {
        sA[r*52 + c2] = 0.f;
        atomicAdd(&sRow[r], -v);
        atomicAdd(&sCol[c2], -v);
      }
      pruned += take; pos += take;
      if (pruned >= NPRUNE) break;
      if (take == 64) continue;
      // blocking entry (lane 'take' holds it): exact re-eval with updated sums
      unsigned int bvb = (unsigned int)__builtin_amdgcn_readlane((int)vb, take);
      int bidx = __builtin_amdgcn_readlane((int)idx, take);
      float bv = __uint_as_float(bvb);
      if (!(bv < 0.f) || bidx >= NF2) { toP2 = true; break; }
      int br = bidx / NF, bc = bidx % NF;
      float sr = sRow[br], sc = sCol[bc];
      bool ok = ((sr - bv) > 0.f) || ((sc - bv) > 0.f);
      if (ok) {
        if (lane == 0) {
          sA[br*52 + bc] = 0.f;
          sRow[br] = sr - bv; sCol[bc] = sc - bv;
        }
        pruned++; pos++;
      } else {
        if (lane == 0) {
          sA[br*52 + bc] = mx;
          sRow[br] = sr + (mx - bv); sCol[bc] = sc + (mx - bv);
        }
        pos++;
      }
    }
    // phase 2: values >= 0 (usually exits in 1 step via frozen-zero rule)
    if (toP2) {
      for (int guard = 0; guard < 40000 && pruned < NPRUNE; guard++) {
        float bv = 3.0e38f; int bidx = NF2;
        for (int u = lane; u < NF2; u += 64) {
          float v = sA[(u / NF)*52 + (u % NF)];
          if (v < bv) { bv = v; bidx = u; }
        }
        for (int o = 32; o > 0; o >>= 1) {
          float ov = __shfl_xor(bv, o, 64);
          int  oi = __shfl_xor(bidx, o, 64);
          if (ov < bv || (ov == bv && oi < bidx)) { bv = ov; bidx = oi; }
        }
        int br = bidx / NF, bc = bidx % NF;
        float sr = sRow[br], sc = sCol[bc];
        bool ok = ((sr - bv) > 0.f) || ((sc - bv) > 0.f);
        if (ok) {
          if (bv == 0.f) break;   // frozen: argmin & ok identical forever, i counts up
          if (lane == 0) { sA[br*52+bc] = 0.f; sRow[br] = sr - bv; sCol[bc] = sc - bv; }
          pruned++;
        } else {
          if (bv == mx) break;    // no-progress safety
          if (lane == 0) { sA[br*52+bc] = mx; sRow[br] = sr + (mx-bv); sCol[bc] = sc + (mx-bv); }
        }
      }
    }
  }
  __syncthreads();

  if (t < NF) {
    float deg = 0.f;
    for (int j = 0; j < NF; j++) {
      float a = sA[t*52 + j];
      float bin = (a != 0.f) ? 1.f : 0.f;
      if (j == t) bin += 1.f;
      deg += bin;
    }
    sDinv[t] = 1.f / sqrtf(deg);
  }
  __syncthreads();

  float* sN = (float*)sKey;   // sKey dead; reuse as norm_adj [51][52]
  for (int u = t; u < NF * 52; u += 512) {
    int r = u / 52, c = u % 52;
    float v = 0.f;
    if (c < NF) {
      float a = sA[r*52 + c];
      float bin = (a != 0.f) ? 1.f : 0.f;
      if (r == c) bin += 1.f;
      v = sDinv[r] * bin * sDinv[c];
    }
    sN[u] = v;
  }
  __syncthreads();

  // E2 = norm_adj @ embed  [51][12]  (D = (norm_adj@embed)@gcn_w_emb^T:
  // reassociated from norm_adj@(embed@gcn_w_emb^T) — 94k MACs vs 291k)
  for (int u = t; u < NF * EMB; u += 512) {
    int i = u / EMB, e = u % EMB;
    float s2 = 0.f;
    for (int j = 0; j < NF; j++) s2 += sN[i*52 + j] * sEmb[j*EMB + e];
    sE2[u] = s2;
  }

  char* wsb = (char*)ws;
  f16* adjT = (f16*)(wsb + WS_ADJ);
  for (int u = t; u < 64*72; u += 512) {
    int r = u / 72, k = u % 72;
    adjT[u] = (f16)((r < NF && k < NF) ? sN[r*52 + k] : 0.f);
  }
  f16* wxT = (f16*)(wsb + WS_WX);
  for (int u = t; u < 112*136; u += 512) {
    int nn = u / 136, k = u % 136;
    wxT[u] = (f16)((nn < WIN && k < WIN) ? gcn_w[nn*FIN + k] : 0.f);
  }
  f16* w1T = (f16*)(wsb + WS_W1);
  for (int u = t; u < 64*136; u += 512) {
    int nn = u / 136, k = u % 136;
    w1T[u] = (f16)((nn < HID && k < WIN) ? w1[nn*WIN + k] : 0.f);
  }
  f16* w2T = (f16*)(wsb + WS_W2);
  for (int u = t; u < 112*72; u += 512) {
    int nn = u / 72, k = u % 72;
    w2T[u] = (f16)((nn < WIN && k < HID) ? w2[nn*HID + k] : 0.f);
  }
  __syncthreads();   // sE2 ready
  float* Dp = (float*)(wsb + WS_D);
  for (int u = t; u < NF * 112; u += 512) {
    int i = u / 112, w = u % 112;
    float s2 = 0.f;
    if (w < WIN) {
      for (int e = 0; e < EMB; e++) s2 += sE2[i*EMB + e] * gcn_w[w*FIN + WIN + e];
      s2 += gcn_b[w];
    }
    Dp[u] = s2;
  }
}

// ---------------- Kernel 2: persistent fused MFMA forward ----------------
// 256 blocks x 512 thr; each block streams 16 sample-pairs. Weights staged once.
// S2/S3/S4 computed with SWAPPED MFMA operand roles (weight frag first, row frag
// second): D[a_row->(4g+r2)][b_row->c] then gives each lane 4 CONSECUTIVE columns
// of one row => all LDS writes are b64, D-bias reads are f32x4, and the final
// store is a coalesced float4 (was: 44 scalar ds_writes + 28 scalar global
// stores per wave per pair, ~4-way bank-conflicted).
// adjT/w2T fragments are static => held in persistent registers across pairs.
__global__ __launch_bounds__(512, 1) void forward_kernel(
    const float* __restrict__ x, const float* __restrict__ b1g,
    const float* __restrict__ b2g, const void* __restrict__ ws,
    float* __restrict__ out, int nPairs, int ppb) {
  __shared__ __align__(16) char smem[LDS_TOTAL];
  f16* wxT  = (f16*)(smem + WS_WX);
  f16* w1T  = (f16*)(smem + WS_W1);
  f16* adjTl = (f16*)(smem + WS_ADJ);
  f16* w2Tl  = (f16*)(smem + WS_W2);
  const float* Dl = (const float*)(smem + WS_D);
  f16* R1 = (f16*)(smem + LDS_R1);     // [120][136]: sX then h2
  f16* yT = (f16*)(smem + LDS_R2);     // [2][112][72]
  f16* h3 = (f16*)(smem + LDS_R2);     // [120][72] (aliases yT; dead by then)

  const int t = threadIdx.x;
  const int wv = t >> 6, lane = t & 63;
  const int c = lane & 15, g = lane >> 4;
  const int s = wv >> 2, mt = wv & 3;
  const int rowA = 51*s + 16*mt + c;      // A/B-row for row-indexed stages

  // one-time: stage weights (96064 B linear), zero activation regions
  {
    const f32x4* w4 = (const f32x4*)ws;
    f32x4* s4 = (f32x4*)smem;
    #pragma unroll
    for (int u = 0; u < 12; u++) { int i = t + u*512; if (i < 6004) s4[i] = w4[i]; }
    f32x4 z = {0.f,0.f,0.f,0.f};
    f32x4* za = (f32x4*)(smem + LDS_R1);
    #pragma unroll
    for (int u = 0; u < 8; u++) { int i = t + u*512; if (i < 4056) za[i] = z; }
  }

  const int pair0 = blockIdx.x * ppb;
  float4 p0, p1, p2, p3, p4;
  if (pair0 < nPairs) {
    const float4* xb = (const float4*)(x + (size_t)pair0 * 10200);
    p0 = xb[t]; p1 = xb[t+512]; p2 = xb[t+1024]; p3 = xb[t+1536];
    if (t < 502) p4 = xb[t+2048];
  }
  __syncthreads();

  // persistent register fragments of static weights (reloaded never)
  f16x8 adjf[4][2];
  #pragma unroll
  for (int N = 0; N < 4; N++) {
    const f16* bp = &adjTl[(16*N + c)*72 + 8*g];
    adjf[N][0] = *(const f16x8*)(bp + 0);
    adjf[N][1] = *(const f16x8*)(bp + 32);
  }
  f16x8 w2f[7][2];
  #pragma unroll
  for (int N = 0; N < 7; N++) {
    const f16* ap = &w2Tl[(16*N + c)*72 + 8*g];
    w2f[N][0] = *(const f16x8*)(ap + 0);
    w2f[N][1] = *(const f16x8*)(ap + 32);
  }

  #pragma unroll 1
  for (int p = 0; p < ppb; p++) {
    const int pairIdx = pair0 + p;
    const bool valid = pairIdx < nPairs;

    // ---- write prefetched x -> sX f16 [row][win] (contiguous b64, no conflicts) ----
    if (valid) {
      #define STV(PV, V) { int row = (V)/25, q4 = ((V)%25)*4; \
        f16x4 hv = {(f16)(PV).x,(f16)(PV).y,(f16)(PV).z,(f16)(PV).w}; \
        *(f16x4*)&R1[row*136 + q4] = hv; }
      STV(p0, t); STV(p1, t+512); STV(p2, t+1024); STV(p3, t+1536);
      if (t < 502) STV(p4, t+2048);
      #undef STV
    }
    __syncthreads();   // bar A: sX ready; all waves past S4(p-1)

    // issue next pair's prefetch (latency hidden under S1..S4)
    if (p + 1 < ppb && pairIdx + 1 < nPairs) {
      const float4* xb = (const float4*)(x + (size_t)(pairIdx+1) * 10200);
      p0 = xb[t]; p1 = xb[t+512]; p2 = xb[t+1024]; p3 = xb[t+1536];
      if (t < 502) p4 = xb[t+2048];
    }

    // ---- S1: y = x @ Wx^T ; write yT[s][win][node] (transposed, b64) ----
    if (valid) {
      const f16* aB = &R1[rowA*136];
      const f16x8 a0 = *(const f16x8*)(aB +  0 + 8*g);
      const f16x8 a1 = *(const f16x8*)(aB + 32 + 8*g);
      const f16x8 a2 = *(const f16x8*)(aB + 64 + 8*g);
      const f16x8 a3 = *(const f16x8*)(aB + 96 + 8*g);
      f16* yTs = yT + s*8064;
      const int nodeW = 16*mt + 4*g;
      #pragma unroll
      for (int N = 0; N < 7; N++) {
        const f16* bp = &wxT[(16*N + c)*136 + 8*g];
        f32x4 acc = {0.f,0.f,0.f,0.f};
        acc = __builtin_amdgcn_mfma_f32_16x16x32_f16(a0, *(const f16x8*)(bp +  0), acc, 0, 0, 0);
        acc = __builtin_amdgcn_mfma_f32_16x16x32_f16(a1, *(const f16x8*)(bp + 32), acc, 0, 0, 0);
        acc = __builtin_amdgcn_mfma_f32_16x16x32_f16(a2, *(const f16x8*)(bp + 64), acc, 0, 0, 0);
        acc = __builtin_amdgcn_mfma_f32_16x16x32_f16(a3, *(const f16x8*)(bp + 96), acc, 0, 0, 0);
        const int col = 16*N + c;
        if (mt < 3) {
          f16x4 hv = {(f16)acc[0],(f16)acc[1],(f16)acc[2],(f16)acc[3]};
          *(f16x4*)&yTs[col*72 + nodeW] = hv;
        } else {
          #pragma unroll
          for (int r2 = 0; r2 < 4; r2++)
            if (nodeW + r2 < NF) yTs[col*72 + nodeW + r2] = (f16)acc[r2];
        }
      }
    }
    __syncthreads();   // bar B: yT ready; sX reads done

    // ---- S2 (swapped): h2 = relu(adj @ y + D). A-frag = yT win-rows,
    // B-frag = adj node-rows => lane holds h2[16N+c][16wt+4g..+3] => b64 writes.
    // 14 tasks = 2 samples x 7 win-tiles over 8 waves.
    if (valid) {
      for (int task = wv; task < 14; task += 8) {
        const int s2 = (task >= 7) ? 1 : 0;
        const int wt = task - 7*s2;
        const f16* ap = &yT[s2*8064 + (16*wt + c)*72 + 8*g];
        const f16x8 a0 = *(const f16x8*)(ap + 0);
        const f16x8 a1 = *(const f16x8*)(ap + 32);
        #pragma unroll
        for (int N = 0; N < 4; N++) {
          f32x4 acc = {0.f,0.f,0.f,0.f};
          acc = __builtin_amdgcn_mfma_f32_16x16x32_f16(a0, adjf[N][0], acc, 0, 0, 0);
          acc = __builtin_amdgcn_mfma_f32_16x16x32_f16(a1, adjf[N][1], acc, 0, 0, 0);
          const int nd = 16*N + c;
          if (nd < NF) {
            const f32x4 dv = *(const f32x4*)&Dl[nd*112 + 16*wt + 4*g];
            f16x4 hv = {(f16)fmaxf(acc[0]+dv[0],0.f),(f16)fmaxf(acc[1]+dv[1],0.f),
                        (f16)fmaxf(acc[2]+dv[2],0.f),(f16)fmaxf(acc[3]+dv[3],0.f)};
            *(f16x4*)&R1[(51*s2 + nd)*136 + 16*wt + 4*g] = hv;
          }
        }
      }
    }
    __syncthreads();   // bar C: h2 ready; yT reads done

    // ---- S3 (swapped): h3 = tanh(h2 @ w1^T + b1). A-frag = w1 n-rows,
    // B-frag = h2 rows (wave's own tile) => lane writes h3[rowA][16N+4g..+3] b64.
    // (Row-overlap between (s=0,mt=3) and (s=1,mt=0) waves writes IDENTICAL
    //  values — benign.)
    if (valid) {
      const f16* bB = &R1[rowA*136 + 8*g];
      const f16x8 hb0 = *(const f16x8*)(bB +  0);
      const f16x8 hb1 = *(const f16x8*)(bB + 32);
      const f16x8 hb2 = *(const f16x8*)(bB + 64);
      const f16x8 hb3 = *(const f16x8*)(bB + 96);
      #pragma unroll
      for (int N = 0; N < 4; N++) {
        const f16* ap = &w1T[(16*N + c)*136 + 8*g];
        f32x4 acc = {0.f,0.f,0.f,0.f};
        acc = __builtin_amdgcn_mfma_f32_16x16x32_f16(*(const f16x8*)(ap +  0), hb0, acc, 0, 0, 0);
        acc = __builtin_amdgcn_mfma_f32_16x16x32_f16(*(const f16x8*)(ap + 32), hb1, acc, 0, 0, 0);
        acc = __builtin_amdgcn_mfma_f32_16x16x32_f16(*(const f16x8*)(ap + 64), hb2, acc, 0, 0, 0);
        acc = __builtin_amdgcn_mfma_f32_16x16x32_f16(*(const f16x8*)(ap + 96), hb3, acc, 0, 0, 0);
        const int colb = 16*N + 4*g;
        float4 bv = {0.f, 0.f, 0.f, 0.f};
        if (colb < HID) bv = *(const float4*)&b1g[colb];
        f16x4 hv = {(f16)fast_tanh(acc[0]+bv.x),(f16)fast_tanh(acc[1]+bv.y),
                    (f16)fast_tanh(acc[2]+bv.z),(f16)fast_tanh(acc[3]+bv.w)};
        *(f16x4*)&h3[rowA*72 + colb] = hv;
      }
    }
    __syncthreads();   // bar D: all h2 reads done (next sX write safe)

    // ---- S4 (swapped): out = tanh(h3 @ w2^T + b2). A-frag = w2 n-rows (in
    // persistent regs), B-frag = h3 rows (own tile) => coalesced float4 stores.
    if (valid) {
      const f16* bB = &h3[rowA*72 + 8*g];
      const f16x8 hb0 = *(const f16x8*)(bB +  0);
      const f16x8 hb1 = *(const f16x8*)(bB + 32);
      const bool rowOk = (16*mt + c) < NF;
      float* ob = out + (size_t)pairIdx * 10200 + (size_t)rowA * 100;
      #pragma unroll
      for (int N = 0; N < 7; N++) {
        f32x4 acc = {0.f,0.f,0.f,0.f};
        acc = __builtin_amdgcn_mfma_f32_16x16x32_f16(w2f[N][0], hb0, acc, 0, 0, 0);
        acc = __builtin_amdgcn_mfma_f32_16x16x32_f16(w2f[N][1], hb1, acc, 0, 0, 0);
        const int colb = 16*N + 4*g;
        if (rowOk && colb < WIN) {
          const float4 bv = *(const float4*)&b2g[colb];
          float4 ov = {fast_tanh(acc[0]+bv.x), fast_tanh(acc[1]+bv.y),
                       fast_tanh(acc[2]+bv.z), fast_tanh(acc[3]+bv.w)};
          *(float4*)&ob[colb] = ov;
        }
      }
    }
  }
}

extern "C" void kernel_launch(void* const* d_in, const int* in_sizes, int n_in,
                              void* d_out, int out_size, void* d_ws, size_t ws_size,
                              hipStream_t stream) {
  const float* x     = (const float*)d_in[0];
  const float* embed = (const float*)d_in[2];
  const float* gcn_w = (const float*)d_in[3];
  const float* gcn_b = (const float*)d_in[4];
  const float* w1    = (const float*)d_in[5];
  const float* b1    = (const float*)d_in[6];
  const float* w2    = (const float*)d_in[7];
  const float* b2    = (const float*)d_in[8];
  float* out = (float*)d_out;

  const int batch = in_sizes[0] / (NF * WIN);   // 8192
  const int nPairs = batch / 2;                 // 4096
  const int blocks = 256;
  const int ppb = (nPairs + blocks - 1) / blocks;  // 16

  prune_kernel<<<1, 512, 0, stream>>>(embed, gcn_w, gcn_b, w1, w2, d_ws);
  forward_kernel<<<blocks, 512, 0, stream>>>(x, b1, b2, d_ws, out, nPairs, ppb);
}

// Round 2
// 172.456 us; speedup vs baseline: 1.9056x; 1.1686x over previous
//
#include <hip/hip_runtime.h>
#include <hip/hip_bf16.h>
#include <stdint.h>

#define NF 51
#define NF2 (51*51)
#define WIN 100
#define EMB 12
#define FIN 112
#define HID 60
#define NPRUNE 1561
#define SORTN 4096

// ws byte offsets (total 96064 B) — contiguous; forward stages with ONE linear copy
#define WS_ADJ   0          // f16 [64][72]   adj[m][k] (m,k<51 else 0)
#define WS_WX    9216       // f16 [112][136] Wx[n][k]  (n<100,k<100 else 0)
#define WS_W1    39680      // f16 [64][136]  w1[n][k]  (n<60,k<100 else 0)
#define WS_W2    57088      // f16 [112][72]  w2[n][k]  (n<100,k<60 else 0)
#define WS_D     73216      // f32 [51][112]  D = norm_adj@C_emb + gcn_b (col<100 else 0)
#define WS_TOTAL 96064

// forward LDS layout (bytes)
#define LDS_R1   96064      // f16 [120][136]  sX (x rows) / h2, alternating
#define LDS_R2   128704     // f16 yT [2][112][72]  /  h3 [120][72], alternating
#define LDS_TOTAL 160960

typedef _Float16 f16;
typedef _Float16 f16x8 __attribute__((ext_vector_type(8)));
typedef _Float16 f16x4 __attribute__((ext_vector_type(4)));
typedef float f32x4 __attribute__((ext_vector_type(4)));

__device__ __forceinline__ float fast_tanh(float x) {
  float xa = fminf(fmaxf(x, -15.f), 15.f);
  float e = __expf(2.f * xa);
  return (e - 1.f) * __builtin_amdgcn_rcpf(e + 1.f);
}

// T4 barrier: LDS-visibility wait only; vmcnt NOT drained => prefetch loads stay
// in flight across barriers and stores never block (the __syncthreads drain was
// the main stall: 4 full vmem drains per pair-iteration).
#define BAR() do { asm volatile("s_waitcnt lgkmcnt(0)" ::: "memory"); \
  __builtin_amdgcn_s_barrier(); asm volatile("" ::: "memory"); } while (0)

// ---------------- Kernel 1: graph construction + greedy prune + prep ----------------
// grid = 2 blocks: block 1 stages the prune-independent weights (wxT/w1T/w2T)
// concurrently; block 0 does cos -> prune -> adjT/D.
__global__ __launch_bounds__(512) void prune_kernel(const float* __restrict__ embed,
                                                    const float* __restrict__ gcn_w,
                                                    const float* __restrict__ gcn_b,
                                                    const float* __restrict__ w1,
                                                    const float* __restrict__ w2,
                                                    void* __restrict__ ws) {
  const int t = threadIdx.x;
  char* wsb = (char*)ws;

  if (blockIdx.x == 1) {
    f16* wxT = (f16*)(wsb + WS_WX);
    for (int u = t; u < 112*136; u += 512) {
      int nn = u / 136, k = u % 136;
      wxT[u] = (f16)((nn < WIN && k < WIN) ? gcn_w[nn*FIN + k] : 0.f);
    }
    f16* w1T = (f16*)(wsb + WS_W1);
    for (int u = t; u < 64*136; u += 512) {
      int nn = u / 136, k = u % 136;
      w1T[u] = (f16)((nn < HID && k < WIN) ? w1[nn*WIN + k] : 0.f);
    }
    f16* w2T = (f16*)(wsb + WS_W2);
    for (int u = t; u < 112*72; u += 512) {
      int nn = u / 72, k = u % 72;
      w2T[u] = (f16)((nn < WIN && k < HID) ? w2[nn*HID + k] : 0.f);
    }
    return;
  }

  __shared__ float sA[NF * 52];
  __shared__ unsigned long long sKey[SORTN];
  __shared__ float sNrm[NF];
  __shared__ float sDinv[NF];
  __shared__ float sRow[NF];
  __shared__ float sCol[NF];
  __shared__ float sEmb[NF * EMB];
  __shared__ float sE2[NF * EMB];
  __shared__ int sCnt[17];
  __shared__ int sBad;
  __shared__ int sTotal;

  for (int u = t; u < NF * EMB; u += 512) sEmb[u] = embed[u];
  if (t == 0) { sBad = 0; sTotal = 0; }
  __syncthreads();
  if (t < NF) {
    float s = 0.f;
    for (int e = 0; e < EMB; e++) { float w = sEmb[t*EMB + e]; s += w * w; }
    sNrm[t] = sqrtf(s);
  }
  __syncthreads();
  for (int u = t; u < NF2; u += 512) {
    int r = u / NF, c = u % NF;
    float d = 0.f;
    for (int e = 0; e < EMB; e++) d += sEmb[r*EMB + e] * sEmb[c*EMB + e];
    sA[r*52 + c] = d / (sNrm[r] * sNrm[c]);
  }
  __syncthreads();

  // initial row/col sums
  if (t < NF) {
    float rs = 0.f, cs = 0.f;
    for (int j = 0; j < NF; j++) { rs += sA[t*52 + j]; cs += sA[j*52 + t]; }
    sRow[t] = rs; sCol[t] = cs;
  }
  __syncthreads();

  // ---- FAST-PATH check: during the negative phase sums only INCREASE and
  // ok=(sum-v>0) is monotone in sum, so ok under INITIAL sums true for EVERY
  // negative => the serial walk accepts all negatives (order irrelevant).
  // With count <= NPRUNE the final A is exactly "negatives zeroed" and phase 2
  // is the frozen-zero no-op (diag=1 keeps all row sums > 0). No sort needed.
  {
    int myCnt = 0, myBad = 0;
    for (int u = t; u < NF2; u += 512) {
      int r = u / NF, c = u % NF;
      float v = sA[r*52 + c];
      if (v < 0.f) {
        myCnt++;
        bool ok0 = ((sRow[r] - v) > 0.f) || ((sCol[c] - v) > 0.f);
        if (!ok0) myBad = 1;
      }
    }
    if (myCnt) atomicAdd(&sTotal, myCnt);
    if (myBad) atomicExch(&sBad, 1);
  }
  __syncthreads();
  const bool fastPath = (sBad == 0) && (sTotal > 0) && (sTotal <= NPRUNE);

  if (fastPath) {
    for (int u = t; u < NF2; u += 512) {
      int r = u / NF, c = u % NF;
      if (sA[r*52 + c] < 0.f) sA[r*52 + c] = 0.f;
    }
  } else {
    // ---- SLOW PATH (exact; compaction + bitonic sort + ballot walk) ----
    int myCnt = 0;
    for (int u = t; u < NF2; u += 512)
      myCnt += (sA[(u / NF)*52 + (u % NF)] < 0.f) ? 1 : 0;
    int incl = myCnt;
    for (int o = 1; o < 64; o <<= 1) {
      int nb = __shfl_up(incl, o, 64);
      if ((t & 63) >= o) incl += nb;
    }
    if ((t & 63) == 63) sCnt[t >> 6] = incl;
    __syncthreads();
    if (t == 0) {
      int run = 0;
      for (int j = 0; j < 8; j++) { int v = sCnt[j]; sCnt[8 + j] = run; run += v; }
      sCnt[16] = run;
    }
    __syncthreads();
    const int total = sCnt[16];
    const int n = (total <= 2048) ? 2048 : SORTN;
    {
      int cpos = sCnt[8 + (t >> 6)] + (incl - myCnt);
      for (int u = t; u < NF2; u += 512) {
        float v = sA[(u / NF)*52 + (u % NF)];
        if (v < 0.f) {
          unsigned int b = __float_as_uint(v);
          sKey[cpos++] = ((unsigned long long)(~b) << 32) | (unsigned int)u;
        }
      }
      for (int u = total + t; u < n; u += 512) sKey[u] = ~0ull;
    }
    __syncthreads();
    for (int kk = 2; kk <= n; kk <<= 1) {
      for (int jj = kk >> 1; jj > 0; jj >>= 1) {
        for (int u = t; u < n; u += 512) {
          int l = u ^ jj;
          if (l > u) {
            unsigned long long a = sKey[u], b = sKey[l];
            bool up = ((u & kk) == 0);
            if ((a > b) == up) { sKey[u] = b; sKey[l] = a; }
          }
        }
        __syncthreads();
      }
    }

    if (t < 64) {
      const int lane = t;
      float mx = -3.0e38f;
      for (int u = lane; u < NF2; u += 64) mx = fmaxf(mx, sA[(u / NF)*52 + (u % NF)]);
      for (int o = 32; o > 0; o >>= 1) mx = fmaxf(mx, __shfl_xor(mx, o, 64));

      int pruned = 0, pos = 0;
      bool toP2 = false;
      while (pruned < NPRUNE && !toP2) {
        int myi = pos + lane;
        unsigned long long kv = (myi < n) ? sKey[myi] : ~0ull;
        unsigned int mb  = (unsigned int)(kv >> 32);
        unsigned int idx = (unsigned int)kv;
        unsigned int vb  = (mb & 0x80000000u) ? (mb & 0x7FFFFFFFu) : ~mb;
        float v = __uint_as_float(vb);
        bool elig = (v < 0.f) && (idx < (unsigned)NF2);
        int r = 0, c2 = 0; bool okl = false;
        if (elig) {
          r = (int)(idx / NF); c2 = (int)(idx % NF);
          float sr = sRow[r], sc = sCol[c2];
          okl = ((sr - v) > 0.f) || ((sc - v) > 0.f);
        }
        unsigned long long bal = __ballot(okl);
        unsigned long long nb = ~bal;
        int nok = (nb == 0ull) ? 64 : (int)__builtin_ctzll(nb);
        int rem = NPRUNE - pruned;
        int take = nok < rem ? nok : rem;
        if (lane < take) {
          sA[r*52 + c2] = 0.f;
          atomicAdd(&sRow[r], -v);
          atomicAdd(&sCol[c2], -v);
        }
        pruned += take; pos += take;
        if (pruned >= NPRUNE) break;
        if (take == 64) continue;
        unsigned int bvb = (unsigned int)__builtin_amdgcn_readlane((int)vb, take);
        int bidx = __builtin_amdgcn_readlane((int)idx, take);
        float bv = __uint_as_float(bvb);
        if (!(bv < 0.f) || bidx >= NF2) { toP2 = true; break; }
        int br = bidx / NF, bc = bidx % NF;
        float sr = sRow[br], sc = sCol[bc];
        bool ok = ((sr - bv) > 0.f) || ((sc - bv) > 0.f);
        if (ok) {
          if (lane == 0) {
            sA[br*52 + bc] = 0.f;
            sRow[br] = sr - bv; sCol[bc] = sc - bv;
          }
          pruned++; pos++;
        } else {
          if (lane == 0) {
            sA[br*52 + bc] = mx;
            sRow[br] = sr + (mx - bv); sCol[bc] = sc + (mx - bv);
          }
          pos++;
        }
      }
      if (toP2) {
        for (int guard = 0; guard < 40000 && pruned < NPRUNE; guard++) {
          float bv = 3.0e38f; int bidx = NF2;
          for (int u = lane; u < NF2; u += 64) {
            float v = sA[(u / NF)*52 + (u % NF)];
            if (v < bv) { bv = v; bidx = u; }
          }
          for (int o = 32; o > 0; o >>= 1) {
            float ov = __shfl_xor(bv, o, 64);
            int  oi = __shfl_xor(bidx, o, 64);
            if (ov < bv || (ov == bv && oi < bidx)) { bv = ov; bidx = oi; }
          }
          int br = bidx / NF, bc = bidx % NF;
          float sr = sRow[br], sc = sCol[bc];
          bool ok = ((sr - bv) > 0.f) || ((sc - bv) > 0.f);
          if (ok) {
            if (bv == 0.f) break;
            if (lane == 0) { sA[br*52+bc] = 0.f; sRow[br] = sr - bv; sCol[bc] = sc - bv; }
            pruned++;
          } else {
            if (bv == mx) break;
            if (lane == 0) { sA[br*52+bc] = mx; sRow[br] = sr + (mx-bv); sCol[bc] = sc + (mx-bv); }
          }
        }
      }
    }
  }
  __syncthreads();

  if (t < NF) {
    float deg = 0.f;
    for (int j = 0; j < NF; j++) {
      float a = sA[t*52 + j];
      float bin = (a != 0.f) ? 1.f : 0.f;
      if (j == t) bin += 1.f;
      deg += bin;
    }
    sDinv[t] = 1.f / sqrtf(deg);
  }
  __syncthreads();

  float* sN = (float*)sKey;   // sKey dead; reuse as norm_adj [51][52]
  for (int u = t; u < NF * 52; u += 512) {
    int r = u / 52, c = u % 52;
    float v = 0.f;
    if (c < NF) {
      float a = sA[r*52 + c];
      float bin = (a != 0.f) ? 1.f : 0.f;
      if (r == c) bin += 1.f;
      v = sDinv[r] * bin * sDinv[c];
    }
    sN[u] = v;
  }
  __syncthreads();

  // E2 = norm_adj @ embed  [51][12]  (D = (norm_adj@embed)@gcn_w_emb^T)
  for (int u = t; u < NF * EMB; u += 512) {
    int i = u / EMB, e = u % EMB;
    float s2 = 0.f;
    for (int j = 0; j < NF; j++) s2 += sN[i*52 + j] * sEmb[j*EMB + e];
    sE2[u] = s2;
  }

  f16* adjT = (f16*)(wsb + WS_ADJ);
  for (int u = t; u < 64*72; u += 512) {
    int r = u / 72, k = u % 72;
    adjT[u] = (f16)((r < NF && k < NF) ? sN[r*52 + k] : 0.f);
  }
  __syncthreads();   // sE2 ready
  float* Dp = (float*)(wsb + WS_D);
  for (int u = t; u < NF * 112; u += 512) {
    int i = u / 112, w = u % 112;
    float s2 = 0.f;
    if (w < WIN) {
      for (int e = 0; e < EMB; e++) s2 += sE2[i*EMB + e] * gcn_w[w*FIN + WIN + e];
      s2 += gcn_b[w];
    }
    Dp[u] = s2;
  }
}

// ---------------- Kernel 2: persistent fused MFMA forward ----------------
// 256 blocks x 512 thr; each block streams 16 sample-pairs. Weights staged once.
// S2/S3/S4 use SWAPPED MFMA operand roles (b64 LDS writes, float4 stores).
// adjT/w2T fragments + b1/b2 biases held in persistent registers.
// Barriers are raw s_barrier + lgkmcnt(0) only (T4): prefetch loads span the
// whole iteration; stores never block a barrier.
__global__ __launch_bounds__(512, 1) void forward_kernel(
    const float* __restrict__ x, const float* __restrict__ b1g,
    const float* __restrict__ b2g, const void* __restrict__ ws,
    float* __restrict__ out, int nPairs, int ppb) {
  __shared__ __align__(16) char smem[LDS_TOTAL];
  f16* wxT  = (f16*)(smem + WS_WX);
  f16* w1T  = (f16*)(smem + WS_W1);
  f16* adjTl = (f16*)(smem + WS_ADJ);
  f16* w2Tl  = (f16*)(smem + WS_W2);
  const float* Dl = (const float*)(smem + WS_D);
  f16* R1 = (f16*)(smem + LDS_R1);     // [120][136]: sX then h2
  f16* yT = (f16*)(smem + LDS_R2);     // [2][112][72]
  f16* h3 = (f16*)(smem + LDS_R2);     // [120][72] (aliases yT; dead by then)

  const int t = threadIdx.x;
  const int wv = t >> 6, lane = t & 63;
  const int c = lane & 15, g = lane >> 4;
  const int s = wv >> 2, mt = wv & 3;
  const int rowA = 51*s + 16*mt + c;      // A/B-row for row-indexed stages

  // one-time: stage weights (96064 B linear), zero activation regions
  {
    const f32x4* w4 = (const f32x4*)ws;
    f32x4* s4 = (f32x4*)smem;
    #pragma unroll
    for (int u = 0; u < 12; u++) { int i = t + u*512; if (i < 6004) s4[i] = w4[i]; }
    f32x4 z = {0.f,0.f,0.f,0.f};
    f32x4* za = (f32x4*)(smem + LDS_R1);
    #pragma unroll
    for (int u = 0; u < 8; u++) { int i = t + u*512; if (i < 4056) za[i] = z; }
  }

  const int pair0 = blockIdx.x * ppb;
  float4 p0, p1, p2, p3, p4;
  if (pair0 < nPairs) {
    const float4* xb = (const float4*)(x + (size_t)pair0 * 10200);
    p0 = xb[t]; p1 = xb[t+512]; p2 = xb[t+1024]; p3 = xb[t+1536];
    if (t < 502) p4 = xb[t+2048];
  }

  // hoist biases into registers (removes 11 global loads / thread / pair)
  float4 b1f[4], b2f[7];
  {
    const float4 zf = {0.f,0.f,0.f,0.f};
    const int colb0 = 4*g;
    #pragma unroll
    for (int N = 0; N < 4; N++) {
      int colb = 16*N + colb0;
      b1f[N] = (colb < HID) ? *(const float4*)&b1g[colb] : zf;
    }
    #pragma unroll
    for (int N = 0; N < 7; N++) {
      int colb = 16*N + colb0;
      b2f[N] = (colb < WIN) ? *(const float4*)&b2g[colb] : zf;
    }
  }
  __syncthreads();

  // persistent register fragments of static weights (reloaded never)
  f16x8 adjf[4][2];
  #pragma unroll
  for (int N = 0; N < 4; N++) {
    const f16* bp = &adjTl[(16*N + c)*72 + 8*g];
    adjf[N][0] = *(const f16x8*)(bp + 0);
    adjf[N][1] = *(const f16x8*)(bp + 32);
  }
  f16x8 w2f[7][2];
  #pragma unroll
  for (int N = 0; N < 7; N++) {
    const f16* ap = &w2Tl[(16*N + c)*72 + 8*g];
    w2f[N][0] = *(const f16x8*)(ap + 0);
    w2f[N][1] = *(const f16x8*)(ap + 32);
  }

  #pragma unroll 1
  for (int p = 0; p < ppb; p++) {
    const int pairIdx = pair0 + p;
    const bool valid = pairIdx < nPairs;

    // ---- write prefetched x -> sX f16 [row][win] (contiguous b64) ----
    if (valid) {
      #define STV(PV, V) { int row = (V)/25, q4 = ((V)%25)*4; \
        f16x4 hv = {(f16)(PV).x,(f16)(PV).y,(f16)(PV).z,(f16)(PV).w}; \
        *(f16x4*)&R1[row*136 + q4] = hv; }
      STV(p0, t); STV(p1, t+512); STV(p2, t+1024); STV(p3, t+1536);
      if (t < 502) STV(p4, t+2048);
      #undef STV
    }
    BAR();   // bar A: sX ready; all waves past S4(p-1)

    // issue next pair's prefetch (stays in flight across all raw barriers)
    if (p + 1 < ppb && pairIdx + 1 < nPairs) {
      const float4* xb = (const float4*)(x + (size_t)(pairIdx+1) * 10200);
      p0 = xb[t]; p1 = xb[t+512]; p2 = xb[t+1024]; p3 = xb[t+1536];
      if (t < 502) p4 = xb[t+2048];
    }

    // ---- S1: y = x @ Wx^T ; write yT[s][win][node] (transposed, b64) ----
    if (valid) {
      const f16* aB = &R1[rowA*136];
      const f16x8 a0 = *(const f16x8*)(aB +  0 + 8*g);
      const f16x8 a1 = *(const f16x8*)(aB + 32 + 8*g);
      const f16x8 a2 = *(const f16x8*)(aB + 64 + 8*g);
      const f16x8 a3 = *(const f16x8*)(aB + 96 + 8*g);
      f16* yTs = yT + s*8064;
      const int nodeW = 16*mt + 4*g;
      #pragma unroll
      for (int N = 0; N < 7; N++) {
        const f16* bp = &wxT[(16*N + c)*136 + 8*g];
        f32x4 acc = {0.f,0.f,0.f,0.f};
        acc = __builtin_amdgcn_mfma_f32_16x16x32_f16(a0, *(const f16x8*)(bp +  0), acc, 0, 0, 0);
        acc = __builtin_amdgcn_mfma_f32_16x16x32_f16(a1, *(const f16x8*)(bp + 32), acc, 0, 0, 0);
        acc = __builtin_amdgcn_mfma_f32_16x16x32_f16(a2, *(const f16x8*)(bp + 64), acc, 0, 0, 0);
        acc = __builtin_amdgcn_mfma_f32_16x16x32_f16(a3, *(const f16x8*)(bp + 96), acc, 0, 0, 0);
        const int col = 16*N + c;
        if (mt < 3) {
          f16x4 hv = {(f16)acc[0],(f16)acc[1],(f16)acc[2],(f16)acc[3]};
          *(f16x4*)&yTs[col*72 + nodeW] = hv;
        } else {
          #pragma unroll
          for (int r2 = 0; r2 < 4; r2++)
            if (nodeW + r2 < NF) yTs[col*72 + nodeW + r2] = (f16)acc[r2];
        }
      }
    }
    BAR();   // bar B: yT ready; sX reads done

    // ---- S2 (swapped): h2 = relu(adj @ y + D) -> R1, b64 writes ----
    if (valid) {
      for (int task = wv; task < 14; task += 8) {
        const int s2 = (task >= 7) ? 1 : 0;
        const int wt = task - 7*s2;
        const f16* ap = &yT[s2*8064 + (16*wt + c)*72 + 8*g];
        const f16x8 a0 = *(const f16x8*)(ap + 0);
        const f16x8 a1 = *(const f16x8*)(ap + 32);
        #pragma unroll
        for (int N = 0; N < 4; N++) {
          f32x4 acc = {0.f,0.f,0.f,0.f};
          acc = __builtin_amdgcn_mfma_f32_16x16x32_f16(a0, adjf[N][0], acc, 0, 0, 0);
          acc = __builtin_amdgcn_mfma_f32_16x16x32_f16(a1, adjf[N][1], acc, 0, 0, 0);
          const int nd = 16*N + c;
          if (nd < NF) {
            const f32x4 dv = *(const f32x4*)&Dl[nd*112 + 16*wt + 4*g];
            f16x4 hv = {(f16)fmaxf(acc[0]+dv[0],0.f),(f16)fmaxf(acc[1]+dv[1],0.f),
                        (f16)fmaxf(acc[2]+dv[2],0.f),(f16)fmaxf(acc[3]+dv[3],0.f)};
            *(f16x4*)&R1[(51*s2 + nd)*136 + 16*wt + 4*g] = hv;
          }
        }
      }
    }
    BAR();   // bar C: h2 ready; yT reads done

    // ---- S3 (swapped): h3 = tanh(h2 @ w1^T + b1) -> R2, b64 writes ----
    if (valid) {
      const f16* bB = &R1[rowA*136 + 8*g];
      const f16x8 hb0 = *(const f16x8*)(bB +  0);
      const f16x8 hb1 = *(const f16x8*)(bB + 32);
      const f16x8 hb2 = *(const f16x8*)(bB + 64);
      const f16x8 hb3 = *(const f16x8*)(bB + 96);
      #pragma unroll
      for (int N = 0; N < 4; N++) {
        const f16* ap = &w1T[(16*N + c)*136 + 8*g];
        f32x4 acc = {0.f,0.f,0.f,0.f};
        acc = __builtin_amdgcn_mfma_f32_16x16x32_f16(*(const f16x8*)(ap +  0), hb0, acc, 0, 0, 0);
        acc = __builtin_amdgcn_mfma_f32_16x16x32_f16(*(const f16x8*)(ap + 32), hb1, acc, 0, 0, 0);
        acc = __builtin_amdgcn_mfma_f32_16x16x32_f16(*(const f16x8*)(ap + 64), hb2, acc, 0, 0, 0);
        acc = __builtin_amdgcn_mfma_f32_16x16x32_f16(*(const f16x8*)(ap + 96), hb3, acc, 0, 0, 0);
        const int colb = 16*N + 4*g;
        const float4 bv = b1f[N];
        f16x4 hv = {(f16)fast_tanh(acc[0]+bv.x),(f16)fast_tanh(acc[1]+bv.y),
                    (f16)fast_tanh(acc[2]+bv.z),(f16)fast_tanh(acc[3]+bv.w)};
        *(f16x4*)&h3[rowA*72 + colb] = hv;
      }
    }
    BAR();   // bar D: all h2 reads done (next sX write safe)

    // ---- S4 (swapped): out = tanh(h3 @ w2^T + b2) -> coalesced float4 ----
    if (valid) {
      const f16* bB = &h3[rowA*72 + 8*g];
      const f16x8 hb0 = *(const f16x8*)(bB +  0);
      const f16x8 hb1 = *(const f16x8*)(bB + 32);
      const bool rowOk = (16*mt + c) < NF;
      float* ob = out + (size_t)pairIdx * 10200 + (size_t)rowA * 100;
      #pragma unroll
      for (int N = 0; N < 7; N++) {
        f32x4 acc = {0.f,0.f,0.f,0.f};
        acc = __builtin_amdgcn_mfma_f32_16x16x32_f16(w2f[N][0], hb0, acc, 0, 0, 0);
        acc = __builtin_amdgcn_mfma_f32_16x16x32_f16(w2f[N][1], hb1, acc, 0, 0, 0);
        const int colb = 16*N + 4*g;
        if (rowOk && colb < WIN) {
          const float4 bv = b2f[N];
          float4 ov = {fast_tanh(acc[0]+bv.x), fast_tanh(acc[1]+bv.y),
                       fast_tanh(acc[2]+bv.z), fast_tanh(acc[3]+bv.w)};
          *(float4*)&ob[colb] = ov;
        }
      }
    }
  }
}

extern "C" void kernel_launch(void* const* d_in, const int* in_sizes, int n_in,
                              void* d_out, int out_size, void* d_ws, size_t ws_size,
                              hipStream_t stream) {
  const float* x     = (const float*)d_in[0];
  const float* embed = (const float*)d_in[2];
  const float* gcn_w = (const float*)d_in[3];
  const float* gcn_b = (const float*)d_in[4];
  const float* w1    = (const float*)d_in[5];
  const float* b1    = (const float*)d_in[6];
  const float* w2    = (const float*)d_in[7];
  const float* b2    = (const float*)d_in[8];
  float* out = (float*)d_out;

  const int batch = in_sizes[0] / (NF * WIN);   // 8192
  const int nPairs = batch / 2;                 // 4096
  const int blocks = 256;
  const int ppb = (nPairs + blocks - 1) / blocks;  // 16

  prune_kernel<<<2, 512, 0, stream>>>(embed, gcn_w, gcn_b, w1, w2, d_ws);
  forward_kernel<<<blocks, 512, 0, stream>>>(x, b1, b2, d_ws, out, nPairs, ppb);
}